// Round 7
// baseline (26793.231 us; speedup 1.0000x reference)
//
#include <hip/hip_runtime.h>

#define SEQ 8192
#define H 1024
#define RING 8
#define NB 32          // scan blocks; 4 units per wave, 8 waves per block

typedef unsigned long long ull;
typedef unsigned int v4u __attribute__((ext_vector_type(4)));

// ---------------------------------------------------------------------------
// Projection GEMM (NT): C[i][j] = bias[j] + sum_k A[i][k]*B[j][k]
// (unchanged — not the bottleneck)
// ---------------------------------------------------------------------------
#define KC 32
#define LDT 68

__global__ __launch_bounds__(256) void proj_gemm(
    const float* __restrict__ A,
    const float* __restrict__ B0, const float* __restrict__ b0, float* __restrict__ C0,
    const float* __restrict__ B1, const float* __restrict__ b1, float* __restrict__ C1,
    const float* __restrict__ B2, const float* __restrict__ b2, float* __restrict__ C2)
{
    __shared__ __align__(16) float As[KC * LDT];
    __shared__ __align__(16) float Bs[KC * LDT];

    const float* Bm; const float* bias; float* C;
    if (blockIdx.z == 0)      { Bm = B0; bias = b0; C = C0; }
    else if (blockIdx.z == 1) { Bm = B1; bias = b1; C = C1; }
    else                      { Bm = B2; bias = b2; C = C2; }

    const int j0 = blockIdx.x * 64;
    const int i0 = blockIdx.y * 64;
    const int tid = threadIdx.x;
    const int tx = tid & 15, ty = tid >> 4;
    const int lrow = tid >> 3;
    const int lkq  = tid & 7;

    float acc[4][4];
#pragma unroll
    for (int r = 0; r < 4; r++)
#pragma unroll
        for (int c = 0; c < 4; c++) acc[r][c] = 0.f;

    for (int k0 = 0; k0 < H; k0 += KC) {
#pragma unroll
        for (int half = 0; half < 2; half++) {
            const int row = lrow + half * 32;
            float4 a = *(const float4*)&A[(size_t)(i0 + row) * H + k0 + 4 * lkq];
            As[(4 * lkq + 0) * LDT + row] = a.x;
            As[(4 * lkq + 1) * LDT + row] = a.y;
            As[(4 * lkq + 2) * LDT + row] = a.z;
            As[(4 * lkq + 3) * LDT + row] = a.w;
            float4 b = *(const float4*)&Bm[(size_t)(j0 + row) * H + k0 + 4 * lkq];
            Bs[(4 * lkq + 0) * LDT + row] = b.x;
            Bs[(4 * lkq + 1) * LDT + row] = b.y;
            Bs[(4 * lkq + 2) * LDT + row] = b.z;
            Bs[(4 * lkq + 3) * LDT + row] = b.w;
        }
        __syncthreads();
#pragma unroll
        for (int k = 0; k < KC; k++) {
            float4 a4 = *(const float4*)&As[k * LDT + ty * 4];
            float4 b4 = *(const float4*)&Bs[k * LDT + tx * 4];
            acc[0][0] += a4.x * b4.x; acc[0][1] += a4.x * b4.y;
            acc[0][2] += a4.x * b4.z; acc[0][3] += a4.x * b4.w;
            acc[1][0] += a4.y * b4.x; acc[1][1] += a4.y * b4.y;
            acc[1][2] += a4.y * b4.z; acc[1][3] += a4.y * b4.w;
            acc[2][0] += a4.z * b4.x; acc[2][1] += a4.z * b4.y;
            acc[2][2] += a4.z * b4.z; acc[2][3] += a4.z * b4.w;
            acc[3][0] += a4.w * b4.x; acc[3][1] += a4.w * b4.y;
            acc[3][2] += a4.w * b4.z; acc[3][3] += a4.w * b4.w;
        }
        __syncthreads();
    }

    float4 bi = *(const float4*)&bias[j0 + tx * 4];
#pragma unroll
    for (int r = 0; r < 4; r++) {
        float4 o;
        o.x = acc[r][0] + bi.x; o.y = acc[r][1] + bi.y;
        o.z = acc[r][2] + bi.z; o.w = acc[r][3] + bi.w;
        *(float4*)&C[(size_t)(i0 + ty * 4 + r) * H + j0 + tx * 4] = o;
    }
}

// ---------------------------------------------------------------------------
// GRU scan v5: R4's proven data-as-flag ring (8B (value,tag) pairs, SYSTEM-
// scope publish, exact-tag poll, RING=8, poison-safe) with the poll pressure
// cut 4x: 32 blocks x 512 threads (8 waves; wave owns 4 units). Each wave
// polls 128 units via one dwordx4 (2 pairs)/lane with s_sleep(1) backoff on
// miss — R4's 1024 zero-backoff polling waves were queueing ahead of the
// publish stores at the L3 banks (5.7k cy/step + bimodal 50ms outliers).
// outs row t-1 is written by block (t & 31) — rotating, coalesced float2.
// No election, no memset, no co-residency requirement (32 blocks trivially
// resident).
// ---------------------------------------------------------------------------
__global__ __launch_bounds__(512, 2) void gru_scan(
    const float* __restrict__ xu, const float* __restrict__ xr, const float* __restrict__ xc,
    const float* __restrict__ Wu, const float* __restrict__ Wr, const float* __restrict__ W,
    ull* __restrict__ th,        // RING*H tagged pairs (poison-safe, no init)
    float* __restrict__ out)     // d_out: [H h_final][SEQ*H outputs]
{
    __shared__ float2 hs2[H / 2];

    const int bid  = blockIdx.x;    // 0..31
    const int tid  = threadIdx.x;   // 0..511
    const int wid  = tid >> 6;      // 0..7
    const int lane = tid & 63;
    const int ub   = bid * 32 + wid * 4;   // first of this wave's 4 units

    // weight rows for 3 gates x 4 units; lane's k-slice = {m*256+4*lane..+3}
    // (compiler may keep in VGPRs or re-load under the poll shadow — both fine)
    float4 wg[3][4][4];
    {
        const float* base[3] = { Wu, Wr, W };
#pragma unroll
        for (int g = 0; g < 3; g++) {
            const float4* pg = (const float4*)(base[g] + (size_t)ub * H);
#pragma unroll
            for (int q = 0; q < 4; q++)
#pragma unroll
                for (int m = 0; m < 4; m++)
                    wg[g][q][m] = pg[q * 256 + m * 64 + lane];
        }
    }

    float* outs = out + H;
    float hp = 0.f;                          // lanes 0..3: prev h of unit ub+lane

    for (int t = 0; t < SEQ; t++) {
        // this step's input projections for owned units (hidden under poll)
        float axu = 0.f, axr = 0.f, axc = 0.f;
        if (lane < 4) {
            axu = xu[(size_t)t * H + ub + lane];
            axr = xr[(size_t)t * H + ub + lane];
            axc = xc[(size_t)t * H + ub + lane];
        }

        if (t == 0) {
            hs2[tid] = make_float2(0.f, 0.f);        // h0 = 0
        } else {
            // wave wid polls units wid*128 .. +127 (2 tagged pairs per lane)
            const ull* p = th + ((size_t)(t & (RING - 1)) << 10) + (wid << 7) + (lane << 1);
            v4u x;
            bool ok = false;
            for (;;) {
                if (!ok) {
                    asm volatile(
                        "global_load_dwordx4 %0, %1, off sc0 sc1\n\t"
                        "s_waitcnt vmcnt(0)"
                        : "=&v"(x) : "v"(p) : "memory");
                    ok = ((int)x.y == t) && ((int)x.w == t);
                }
                if (__all(ok)) break;
                __builtin_amdgcn_s_sleep(1);         // backoff: don't thrash L3
            }
            hs2[(wid << 6) + lane] = make_float2(__uint_as_float(x.x), __uint_as_float(x.z));
        }
        __syncthreads();

        if (t > 0 && bid == ((t) & (NB - 1))) {
            // rotating writer: coalesced write of outputs row t-1
            ((float2*)(outs + (size_t)(t - 1) * H))[tid] = hs2[tid];
        }

        const float4* h4 = (const float4*)hs2;
        float s[3][4];
#pragma unroll
        for (int g = 0; g < 3; g++)
#pragma unroll
            for (int q = 0; q < 4; q++) s[g][q] = 0.f;
#pragma unroll
        for (int m = 0; m < 4; m++) {
            float4 h = h4[m * 64 + lane];
#pragma unroll
            for (int g = 0; g < 3; g++)
#pragma unroll
                for (int q = 0; q < 4; q++)
                    s[g][q] += wg[g][q][m].x * h.x + wg[g][q][m].y * h.y
                             + wg[g][q][m].z * h.z + wg[g][q][m].w * h.w;
        }
#pragma unroll
        for (int off = 32; off > 0; off >>= 1)
#pragma unroll
            for (int g = 0; g < 3; g++)
#pragma unroll
                for (int q = 0; q < 4; q++)
                    s[g][q] += __shfl_xor(s[g][q], off, 64);

        if (lane < 4) {
            float su = (lane == 0) ? s[0][0] : (lane == 1) ? s[0][1] : (lane == 2) ? s[0][2] : s[0][3];
            float sr = (lane == 0) ? s[1][0] : (lane == 1) ? s[1][1] : (lane == 2) ? s[1][2] : s[1][3];
            float sw = (lane == 0) ? s[2][0] : (lane == 1) ? s[2][1] : (lane == 2) ? s[2][2] : s[2][3];
            float u    = 1.f / (1.f + __expf(-(axu + su)));
            float r    = 1.f / (1.f + __expf(-(axr + sr)));
            float cand = 1.f / (1.f + __expf(-(axc + r * sw)));
            float hnew = u * hp + (1.f - u) * cand;
            hp = hnew;
            ull pkt = ((ull)(unsigned)(t + 1) << 32) | (ull)__float_as_uint(hnew);
            __hip_atomic_store(th + ((size_t)((t + 1) & (RING - 1)) << 10) + ub + lane,
                               pkt, __ATOMIC_RELAXED, __HIP_MEMORY_SCOPE_SYSTEM);
        }
        __syncthreads();   // hs2 reuse fence
    }

    if (bid == 0) {
        // tag SEQ (slot 0): outputs row SEQ-1 and h_final
        const ull* p = th + ((size_t)(SEQ & (RING - 1)) << 10) + (wid << 7) + (lane << 1);
        v4u x;
        bool ok = false;
        for (;;) {
            if (!ok) {
                asm volatile(
                    "global_load_dwordx4 %0, %1, off sc0 sc1\n\t"
                    "s_waitcnt vmcnt(0)"
                    : "=&v"(x) : "v"(p) : "memory");
                ok = ((int)x.y == SEQ) && ((int)x.w == SEQ);
            }
            if (__all(ok)) break;
            __builtin_amdgcn_s_sleep(1);
        }
        float2 hv = make_float2(__uint_as_float(x.x), __uint_as_float(x.z));
        ((float2*)(outs + (size_t)(SEQ - 1) * H))[(wid << 6) + lane] = hv;
        ((float2*)out)[(wid << 6) + lane] = hv;
    }
}

// ---------------------------------------------------------------------------
extern "C" void kernel_launch(void* const* d_in, const int* in_sizes, int n_in,
                              void* d_out, int out_size, void* d_ws, size_t ws_size,
                              hipStream_t stream) {
    const float* x  = (const float*)d_in[0];
    const float* Uu = (const float*)d_in[1];
    const float* Wu = (const float*)d_in[2];
    const float* Bu = (const float*)d_in[3];
    const float* Ur = (const float*)d_in[4];
    const float* Wr = (const float*)d_in[5];
    const float* Br = (const float*)d_in[6];
    const float* U  = (const float*)d_in[7];
    const float* W  = (const float*)d_in[8];
    const float* B  = (const float*)d_in[9];

    char* ws = (char*)d_ws;
    const size_t MAT = (size_t)SEQ * H * sizeof(float);     // 32 MB
    float* xu = (float*)(ws);
    float* xr = (float*)(ws + MAT);
    float* xc = (float*)(ws + 2 * MAT);
    ull*   th = (ull*)(ws + 3 * MAT);                       // 64 KB ring (no init)

    dim3 g(H / 64, SEQ / 64, 3);
    proj_gemm<<<g, 256, 0, stream>>>(x, Uu, Bu, xu, Ur, Br, xr, U, B, xc);

    gru_scan<<<NB, 512, 0, stream>>>(xu, xr, xc, Wu, Wr, W, th, (float*)d_out);
}